// Round 7
// baseline (447.706 us; speedup 1.0000x reference)
//
#include <hip/hip_runtime.h>
#include <stdint.h>

typedef short short8 __attribute__((ext_vector_type(8)));
typedef float floatx4 __attribute__((ext_vector_type(4)));

#define BIAS 8.0f

__device__ __forceinline__ unsigned short f2bf(float f) {
    unsigned int u = __float_as_uint(f);
    unsigned int r = (u + 0x7FFFu + ((u >> 16) & 1u)) >> 16;   // RNE
    return (unsigned short)r;
}

// ---------------- kernel 0: W -> bf16(-w) in MFMA-B-fragment order
// short8 slot s: T=s>>7 (16-code tile), h=(s>>6)&1 (k half), l=s&63 (lane)
// value[j] = -W[T*16 + (l&15)][h*32 + (l>>4)*8 + j]
__global__ void vq_prep(const float* __restrict__ W, unsigned short* __restrict__ Wsw,
                        float* __restrict__ out0) {
    const int s = blockIdx.x * 256 + threadIdx.x;      // 32768 slots
    const int T = s >> 7;
    const int h = (s >> 6) & 1;
    const int l = s & 63;
    const int code = T * 16 + (l & 15);
    const float* src = W + code * 64 + h * 32 + (l >> 4) * 8;
    const floatx4* sp = (const floatx4*)src;
    floatx4 f0 = sp[0], f1 = sp[1];
    short8 fr;
    fr[0] = (short)f2bf(-f0[0]); fr[1] = (short)f2bf(-f0[1]);
    fr[2] = (short)f2bf(-f0[2]); fr[3] = (short)f2bf(-f0[3]);
    fr[4] = (short)f2bf(-f1[0]); fr[5] = (short)f2bf(-f1[1]);
    fr[6] = (short)f2bf(-f1[2]); fr[7] = (short)f2bf(-f1[3]);
    ((short8*)Wsw)[s] = fr;
    if (s == 0) *out0 = 0.0f;
}

// ---------------- kernel 1: block = 64 rows x 8 waves (512 codes each).
// 512-thread blocks: 4 blocks/CU x 8 waves = 32 waves/CU = 8 waves/SIMD (2048
// threads = chip max). Same K-loop body as the 56-VGPR baseline -> fits the
// 64-VGPR / 8-wave budget; cross-wave TLP hides the per-wave load->MFMA->pack
// dependency chains that starved the 4-wave version at MfmaUtil 26%.
__launch_bounds__(512, 8)
__global__ void vq_main(const float* __restrict__ z, const float* __restrict__ W,
                        const unsigned short* __restrict__ Wsw,
                        float* __restrict__ out, float* __restrict__ partials) {
    __shared__ unsigned int pk_lds[512];   // [wave 0..7][local row 0..63]
    __shared__ unsigned int idx_lds[64];
    __shared__ float ls[8];

    const int tid  = threadIdx.x;
    const int lane = tid & 63;
    const int cg   = tid >> 6;      // wave = code group (512 codes each), 0..7
    const int l15  = lane & 15;
    const int lq   = lane >> 4;
    const int rowbase = blockIdx.x * 64;

    // ---- A fragments: the block's 64 rows x 64 k as bf16 (32 VGPR)
    short8 afrag[4][2];
    #pragma unroll
    for (int mt = 0; mt < 4; ++mt) {
        const float* zp = z + (rowbase + mt * 16 + l15) * 64 + lq * 8;
        #pragma unroll
        for (int h = 0; h < 2; ++h) {
            const floatx4* p = (const floatx4*)(zp + h * 32);
            floatx4 f0 = p[0], f1 = p[1];
            short8 fr;
            fr[0] = (short)f2bf(f0[0]); fr[1] = (short)f2bf(f0[1]);
            fr[2] = (short)f2bf(f0[2]); fr[3] = (short)f2bf(f0[3]);
            fr[4] = (short)f2bf(f1[0]); fr[5] = (short)f2bf(f1[1]);
            fr[6] = (short)f2bf(f1[2]); fr[7] = (short)f2bf(f1[3]);
            afrag[mt][h] = fr;
        }
    }

    const floatx4 bias4 = {BIAS, BIAS, BIAS, BIAS};
    unsigned int minpk[4][4];
    #pragma unroll
    for (int mt = 0; mt < 4; ++mt)
        #pragma unroll
        for (int r = 0; r < 4; ++r) minpk[mt][r] = 0xFFFFFFFFu;

    // ---- K loop: 8 iterations x 4 code-tiles (64 codes/iter, 512 total/wave)
    const short8* __restrict__ bp = (const short8*)Wsw + cg * 4096 + lane;
    unsigned int kidx = (unsigned int)(cg * 512 + l15);
    #pragma unroll 1
    for (int it = 0; it < 8; ++it) {
        short8 b0 = bp[0 * 64];
        short8 b1 = bp[1 * 64];
        short8 b2 = bp[2 * 64];
        short8 b3 = bp[3 * 64];
        short8 b4 = bp[4 * 64];
        short8 b5 = bp[5 * 64];
        short8 b6 = bp[6 * 64];
        short8 b7 = bp[7 * 64];
        bp += 512;
        #pragma unroll
        for (int sub = 0; sub < 4; ++sub) {
            short8 c0, c1;
            if (sub == 0) { c0 = b0; c1 = b1; }
            else if (sub == 1) { c0 = b2; c1 = b3; }
            else if (sub == 2) { c0 = b4; c1 = b5; }
            else { c0 = b6; c1 = b7; }
            const unsigned int kk = kidx + (unsigned int)(sub * 16);
            #pragma unroll
            for (int mt = 0; mt < 4; ++mt) {
                floatx4 acc = __builtin_amdgcn_mfma_f32_16x16x32_bf16(afrag[mt][0], c0, bias4, 0, 0, 0);
                acc = __builtin_amdgcn_mfma_f32_16x16x32_bf16(afrag[mt][1], c1, acc, 0, 0, 0);
                #pragma unroll
                for (int r = 0; r < 4; ++r) {
                    unsigned int p = __float_as_uint(acc[r]) | kk;   // monotone pack
                    minpk[mt][r] = p < minpk[mt][r] ? p : minpk[mt][r];
                }
            }
        }
        kidx += 64;
    }

    // ---- reduce across the 16 code-columns (lane bits 0..3), publish per-wave mins
    #pragma unroll
    for (int mt = 0; mt < 4; ++mt)
        #pragma unroll
        for (int r = 0; r < 4; ++r) {
            unsigned int v = minpk[mt][r];
            #pragma unroll
            for (int m = 1; m < 16; m <<= 1) {
                unsigned int o = (unsigned int)__shfl_xor((int)v, m, 64);
                v = o < v ? o : v;
            }
            if (l15 == 0) pk_lds[cg * 64 + mt * 16 + lq * 4 + r] = v;
        }
    __syncthreads();

    // ---- final argmin per row: 64 threads combine the 8 wave-mins
    if (tid < 64) {
        unsigned int v = pk_lds[tid];
        #pragma unroll
        for (int j = 1; j < 8; ++j) {
            unsigned int u = pk_lds[j * 64 + tid];
            v = u < v ? u : v;
        }
        idx_lds[tid] = v & 0xFFFu;
    }
    __syncthreads();

    // ---- epilogue: 512 threads, 8 threads/row, 8 floats each (coalesced 2KB/wave)
    const int rloc = tid >> 3;                 // 0..63
    const int seg  = (tid & 7) * 8;            // float offset within the row
    const unsigned int idx = idx_lds[rloc];
    const int row = rowbase + rloc;
    const floatx4* wp = (const floatx4*)(W + idx * 64 + seg);
    const floatx4* zp = (const floatx4*)(z + row * 64 + seg);
    floatx4* op = (floatx4*)(out + 1 + row * 64 + seg);
    floatx4 w0 = wp[0], w1 = wp[1];
    floatx4 z0 = zp[0], z1 = zp[1];
    op[0] = w0; op[1] = w1;
    float loss = 0.0f;
    #pragma unroll
    for (int j = 0; j < 4; ++j) {
        float d0 = z0[j] - w0[j];
        float d1 = z1[j] - w1[j];
        loss = fmaf(d0, d0, loss);
        loss = fmaf(d1, d1, loss);
    }
    #pragma unroll
    for (int m = 1; m < 64; m <<= 1) loss += __shfl_xor(loss, m, 64);
    if (lane == 0) ls[cg] = loss;
    __syncthreads();
    if (tid == 0) {
        float t = ((ls[0] + ls[1]) + (ls[2] + ls[3]))
                + ((ls[4] + ls[5]) + (ls[6] + ls[7]));
        partials[blockIdx.x] = t;              // no atomic
    }
}

// ---------------- kernel 2: sum 1024 partials -> out[0]
__global__ void vq_loss(const float* __restrict__ partials, float* __restrict__ out) {
    __shared__ float ls[4];
    const int tid  = threadIdx.x;
    const int lane = tid & 63;
    const int w    = tid >> 6;
    float s = partials[tid] + partials[tid + 256] + partials[tid + 512] + partials[tid + 768];
    #pragma unroll
    for (int m = 1; m < 64; m <<= 1) s += __shfl_xor(s, m, 64);
    if (lane == 0) ls[w] = s;
    __syncthreads();
    if (tid == 0) out[0] = ((ls[0] + ls[1]) + (ls[2] + ls[3])) * (0.25f / 4194304.0f);
}

extern "C" void kernel_launch(void* const* d_in, const int* in_sizes, int n_in,
                              void* d_out, int out_size, void* d_ws, size_t ws_size,
                              hipStream_t stream) {
    (void)in_sizes; (void)n_in; (void)out_size; (void)ws_size;
    const float* z = (const float*)d_in[0];
    const float* W = (const float*)d_in[1];
    unsigned short* Wsw = (unsigned short*)d_ws;               // [0, 512KB)
    float* partials = (float*)((char*)d_ws + (512 << 10));     // 1024 floats
    float* out = (float*)d_out;

    vq_prep<<<128, 256, 0, stream>>>(W, Wsw, out);
    vq_main<<<1024, 512, 0, stream>>>(z, W, Wsw, out, partials);
    vq_loss<<<1, 256, 0, stream>>>(partials, out);
}

// Round 8
// 121.861 us; speedup vs baseline: 3.6739x; 3.6739x over previous
//
#include <hip/hip_runtime.h>
#include <stdint.h>

typedef short short8 __attribute__((ext_vector_type(8)));
typedef float floatx4 __attribute__((ext_vector_type(4)));

#define BIAS 8.0f

__device__ __forceinline__ unsigned short f2bf(float f) {
    unsigned int u = __float_as_uint(f);
    unsigned int r = (u + 0x7FFFu + ((u >> 16) & 1u)) >> 16;   // RNE
    return (unsigned short)r;
}

// ---------------- kernel 0: W -> bf16(-w) in MFMA-B-fragment order
// short8 slot s: T=s>>7 (16-code tile), h=(s>>6)&1 (k half), l=s&63 (lane)
// value[j] = -W[T*16 + (l&15)][h*32 + (l>>4)*8 + j]
__global__ void vq_prep(const float* __restrict__ W, unsigned short* __restrict__ Wsw,
                        float* __restrict__ out0) {
    const int s = blockIdx.x * 256 + threadIdx.x;      // 32768 slots
    const int T = s >> 7;
    const int h = (s >> 6) & 1;
    const int l = s & 63;
    const int code = T * 16 + (l & 15);
    const float* src = W + code * 64 + h * 32 + (l >> 4) * 8;
    const floatx4* sp = (const floatx4*)src;
    floatx4 f0 = sp[0], f1 = sp[1];
    short8 fr;
    fr[0] = (short)f2bf(-f0[0]); fr[1] = (short)f2bf(-f0[1]);
    fr[2] = (short)f2bf(-f0[2]); fr[3] = (short)f2bf(-f0[3]);
    fr[4] = (short)f2bf(-f1[0]); fr[5] = (short)f2bf(-f1[1]);
    fr[6] = (short)f2bf(-f1[2]); fr[7] = (short)f2bf(-f1[3]);
    ((short8*)Wsw)[s] = fr;
    if (s == 0) *out0 = 0.0f;
}

// ---------------- kernel 1: block = 32 rows x 4 waves (T=2 row-tiles/wave).
// Register budget by design: afrag 16 + minpk 8 + sunk loads ~12 + misc -> ~48
// VGPR (< 64 cliff, NOT forced) => 8 blocks/CU x 4 waves = 32 waves/CU =
// 8 waves/SIMD. Grid 2048 fills exactly 8 blocks/CU. TLP (not per-wave
// scheduling) hides the load->MFMA->pack chains that pinned MfmaUtil at 26%.
// Cost accepted: B-stream 2x (1 GB L2 total, ~29us floor at 34.5 TB/s).
__launch_bounds__(256)
__global__ void vq_main(const float* __restrict__ z, const float* __restrict__ W,
                        const unsigned short* __restrict__ Wsw,
                        float* __restrict__ out, float* __restrict__ partials) {
    __shared__ unsigned int pk_lds[128];   // [wave 0..3][local row 0..31]
    __shared__ unsigned int idx_lds[32];
    __shared__ float ls[4];

    const int tid  = threadIdx.x;
    const int lane = tid & 63;
    const int cg   = tid >> 6;      // wave = code group (1024 codes each)
    const int l15  = lane & 15;
    const int lq   = lane >> 4;
    const int rowbase = blockIdx.x * 32;

    // ---- A fragments: the block's 32 rows x 64 k as bf16 (16 VGPR)
    short8 afrag[2][2];
    #pragma unroll
    for (int mt = 0; mt < 2; ++mt) {
        const float* zp = z + (rowbase + mt * 16 + l15) * 64 + lq * 8;
        #pragma unroll
        for (int h = 0; h < 2; ++h) {
            const floatx4* p = (const floatx4*)(zp + h * 32);
            floatx4 f0 = p[0], f1 = p[1];
            short8 fr;
            fr[0] = (short)f2bf(f0[0]); fr[1] = (short)f2bf(f0[1]);
            fr[2] = (short)f2bf(f0[2]); fr[3] = (short)f2bf(f0[3]);
            fr[4] = (short)f2bf(f1[0]); fr[5] = (short)f2bf(f1[1]);
            fr[6] = (short)f2bf(f1[2]); fr[7] = (short)f2bf(f1[3]);
            afrag[mt][h] = fr;
        }
    }

    const floatx4 bias4 = {BIAS, BIAS, BIAS, BIAS};
    unsigned int minpk[2][4];
    #pragma unroll
    for (int mt = 0; mt < 2; ++mt)
        #pragma unroll
        for (int r = 0; r < 4; ++r) minpk[mt][r] = 0xFFFFFFFFu;

    // ---- K loop: 16 iterations x 4 code-tiles (64 codes/iter, 1024 total/wave)
    const short8* __restrict__ bp = (const short8*)Wsw + cg * 8192 + lane;
    unsigned int kidx = (unsigned int)(cg * 1024 + l15);
    #pragma unroll 1
    for (int it = 0; it < 16; ++it) {
        short8 b0 = bp[0 * 64];
        short8 b1 = bp[1 * 64];
        short8 b2 = bp[2 * 64];
        short8 b3 = bp[3 * 64];
        short8 b4 = bp[4 * 64];
        short8 b5 = bp[5 * 64];
        short8 b6 = bp[6 * 64];
        short8 b7 = bp[7 * 64];
        bp += 512;
        #pragma unroll
        for (int sub = 0; sub < 4; ++sub) {
            short8 c0, c1;
            if (sub == 0) { c0 = b0; c1 = b1; }
            else if (sub == 1) { c0 = b2; c1 = b3; }
            else if (sub == 2) { c0 = b4; c1 = b5; }
            else { c0 = b6; c1 = b7; }
            const unsigned int kk = kidx + (unsigned int)(sub * 16);
            #pragma unroll
            for (int mt = 0; mt < 2; ++mt) {
                floatx4 acc = __builtin_amdgcn_mfma_f32_16x16x32_bf16(afrag[mt][0], c0, bias4, 0, 0, 0);
                acc = __builtin_amdgcn_mfma_f32_16x16x32_bf16(afrag[mt][1], c1, acc, 0, 0, 0);
                #pragma unroll
                for (int r = 0; r < 4; ++r) {
                    unsigned int p = __float_as_uint(acc[r]) | kk;   // monotone pack
                    minpk[mt][r] = p < minpk[mt][r] ? p : minpk[mt][r];
                }
            }
        }
        kidx += 64;
    }

    // ---- reduce across the 16 code-columns (lane bits 0..3), publish per-wave mins
    #pragma unroll
    for (int mt = 0; mt < 2; ++mt)
        #pragma unroll
        for (int r = 0; r < 4; ++r) {
            unsigned int v = minpk[mt][r];
            #pragma unroll
            for (int m = 1; m < 16; m <<= 1) {
                unsigned int o = (unsigned int)__shfl_xor((int)v, m, 64);
                v = o < v ? o : v;
            }
            if (l15 == 0) pk_lds[cg * 32 + mt * 16 + lq * 4 + r] = v;
        }
    __syncthreads();

    // ---- final argmin per row: 32 threads combine the 4 wave-mins
    if (tid < 32) {
        unsigned int v = pk_lds[tid];
        #pragma unroll
        for (int j = 1; j < 4; ++j) {
            unsigned int u = pk_lds[j * 32 + tid];
            v = u < v ? u : v;
        }
        idx_lds[tid] = v & 0xFFFu;
    }
    __syncthreads();

    // ---- epilogue: 256 threads, 8 threads/row, 8 floats each (coalesced)
    const int rloc = tid >> 3;                 // 0..31
    const int seg  = (tid & 7) * 8;            // float offset within the row
    const unsigned int idx = idx_lds[rloc];
    const int row = rowbase + rloc;
    const floatx4* wp = (const floatx4*)(W + idx * 64 + seg);
    const floatx4* zp = (const floatx4*)(z + row * 64 + seg);
    floatx4* op = (floatx4*)(out + 1 + row * 64 + seg);
    floatx4 w0 = wp[0], w1 = wp[1];
    floatx4 z0 = zp[0], z1 = zp[1];
    op[0] = w0; op[1] = w1;
    float loss = 0.0f;
    #pragma unroll
    for (int j = 0; j < 4; ++j) {
        float d0 = z0[j] - w0[j];
        float d1 = z1[j] - w1[j];
        loss = fmaf(d0, d0, loss);
        loss = fmaf(d1, d1, loss);
    }
    #pragma unroll
    for (int m = 1; m < 64; m <<= 1) loss += __shfl_xor(loss, m, 64);
    if (lane == 0) ls[cg] = loss;
    __syncthreads();
    if (tid == 0) {
        partials[blockIdx.x] = (ls[0] + ls[1]) + (ls[2] + ls[3]);   // no atomic
    }
}

// ---------------- kernel 2: sum 2048 partials -> out[0]
__global__ void vq_loss(const float* __restrict__ partials, float* __restrict__ out) {
    __shared__ float ls[4];
    const int tid  = threadIdx.x;
    const int lane = tid & 63;
    const int w    = tid >> 6;
    float s = 0.0f;
    #pragma unroll
    for (int k = 0; k < 8; ++k) s += partials[tid + k * 256];
    #pragma unroll
    for (int m = 1; m < 64; m <<= 1) s += __shfl_xor(s, m, 64);
    if (lane == 0) ls[w] = s;
    __syncthreads();
    if (tid == 0) out[0] = ((ls[0] + ls[1]) + (ls[2] + ls[3])) * (0.25f / 4194304.0f);
}

extern "C" void kernel_launch(void* const* d_in, const int* in_sizes, int n_in,
                              void* d_out, int out_size, void* d_ws, size_t ws_size,
                              hipStream_t stream) {
    (void)in_sizes; (void)n_in; (void)out_size; (void)ws_size;
    const float* z = (const float*)d_in[0];
    const float* W = (const float*)d_in[1];
    unsigned short* Wsw = (unsigned short*)d_ws;               // [0, 512KB)
    float* partials = (float*)((char*)d_ws + (512 << 10));     // 2048 floats
    float* out = (float*)d_out;

    vq_prep<<<128, 256, 0, stream>>>(W, Wsw, out);
    vq_main<<<2048, 256, 0, stream>>>(z, W, Wsw, out, partials);
    vq_loss<<<1, 256, 0, stream>>>(partials, out);
}